// Round 10
// baseline (939.341 us; speedup 1.0000x reference)
//
#include <hip/hip_runtime.h>

constexpr int kNodes = 1000000;
constexpr int kEdges = 32000000;

// ---------------- Tile-sorted scatter path (id-record + qtab) ----------------
// 256 buckets x 4096 nodes. Record u32 = (node&4095)<<20 | other_id(20b).
// Scatter is a pure integer counting sort (no value gathers): coalesced edge
// loads -> rank atomic r=atomicAdd(cnt[b]) -> slab[b*72+r] -> per-bucket
// arena segment (16B-aligned) via one gcur atomicAdd/bucket -> NT int4 flush.
// Consumer: streams arena with NONTEMPORAL 4-deep unrolled uint4 loads (16
// records in flight/thread; NT keeps the single-use stream from evicting
// qtab), gathers qtab[other] = q16|deg_bit (4 MB, ~98% L2-hit), one LDS
// atomic per record. PADREC=0xFFFFFFFF -> qtab[0xFFFFF]=0 -> adds 0 to
// lacc[4095]: branchless, harmless.
// Calibrations: R6 direct global atomics = 2.4 ms (memory-side, ~28 G/s).
// R9 accum counters: VALU 2.3%, HBM 12%, conflicts 2.5% -> latency-bound;
// this round tests outstanding-miss depth as the limiter.
constexpr int NB = 256;
constexpr int BSHIFT = 12;
constexpr int BNODES = 4096;
constexpr int NBUSED = (kNodes + BNODES - 1) / BNODES;   // 245
constexpr int EPT = 4096;                 // edges per tile
constexpr int TILES = (kEdges + EPT - 1) / EPT;          // 7813
constexpr int SLOT = 72;                  // slab slots/bucket (72%32=8: low conflict)
constexpr int GP = SLOT / 4;              // int4 groups per slab (18)
constexpr int CAP = 284672;               // per-bucket arena capacity (mult 4), ~20 sigma
constexpr int SPLIT = 2;
constexpr unsigned PADREC = 0xFFFFFFFFu;  // other=0xFFFFF -> qtab entry 0
constexpr unsigned OVFCAP = 8192;
constexpr int QTABN = 1 << 20;            // qtab entries (pow2, covers 20-bit field)

typedef unsigned u32x4 __attribute__((ext_vector_type(4)));  // NT-capable vec

constexpr size_t kArenaBytes = (size_t)NBUSED * CAP * 4;   // ~279 MB
constexpr size_t kCurOff    = kArenaBytes;
constexpr size_t kCurBytes  = (size_t)NB * 64 + 64;        // strided cursors + ovfcnt
constexpr size_t kAccOff    = kCurOff + kCurBytes;
constexpr size_t kAccBytes  = (size_t)SPLIT * kNodes * 4;  // 8 MB
constexpr size_t kQtabOff   = kAccOff + kAccBytes;
constexpr size_t kQtabBytes = (size_t)QTABN * 4;           // 4 MB
constexpr size_t kOvfOff    = kQtabOff + kQtabBytes;
constexpr size_t kOvfBytes  = (size_t)OVFCAP * 8;          // 64 KB
constexpr size_t kWsNeeded  = kOvfOff + kOvfBytes;         // ~291 MB

// qtab[j] = q16(orc[j]) | 0x1000000 (deg bit) for j < kNodes, else 0.
__global__ __launch_bounds__(256) void qtab_build(
        const float* __restrict__ orc, unsigned* __restrict__ qtab,
        unsigned* __restrict__ gcur) {
    if (blockIdx.x == 0) {
        if (threadIdx.x < NB) gcur[threadIdx.x * 16] = 0u;
        if (threadIdx.x == 0) gcur[NB * 16] = 0u;       // overflow counter
    }
    const int i = (blockIdx.x * 256 + threadIdx.x) * 4;
    if (i < kNodes) {                                   // kNodes % 4 == 0
        const float4 v = *reinterpret_cast<const float4*>(orc + i);
        unsigned q0 = __float2uint_rn((v.x + 1.0f) * 32768.0f);
        unsigned q1 = __float2uint_rn((v.y + 1.0f) * 32768.0f);
        unsigned q2 = __float2uint_rn((v.z + 1.0f) * 32768.0f);
        unsigned q3 = __float2uint_rn((v.w + 1.0f) * 32768.0f);
        uint4 q;
        q.x = (q0 > 65535u ? 65535u : q0) | 0x1000000u;
        q.y = (q1 > 65535u ? 65535u : q1) | 0x1000000u;
        q.z = (q2 > 65535u ? 65535u : q2) | 0x1000000u;
        q.w = (q3 > 65535u ? 65535u : q3) | 0x1000000u;
        *reinterpret_cast<uint4*>(qtab + i) = q;
    } else if (i < QTABN) {
        uint4 z; z.x = z.y = z.z = z.w = 0u;
        *reinterpret_cast<uint4*>(qtab + i) = z;
    }
}

__global__ __launch_bounds__(1024) void scatter_sort(
        const int* __restrict__ ei, unsigned* __restrict__ arena,
        unsigned* __restrict__ gcur, unsigned long long* __restrict__ ovf) {
    __shared__ alignas(16) unsigned slab[NB * SLOT];   // 72 KB
    __shared__ unsigned cnt[NB];                       // rank cursors
    __shared__ unsigned pcs[NB];                       // padded counts
    __shared__ unsigned dstadd[NB];                    // arena dst base
    const int tid = threadIdx.x;
    const int t = blockIdx.x;
    const int e0 = t * EPT;
    const int ne = min(EPT, kEdges - e0);   // 4096; last tile 2048
    const int k4 = tid * 4;

    if (tid < NB) cnt[tid] = 0u;
    __syncthreads();

    // phase 1: coalesced edge loads -> rank + slab store. No value gathers.
    if (k4 < ne) {
        const int4 s4 = *reinterpret_cast<const int4*>(ei + e0 + k4);
        const int4 d4 = *reinterpret_cast<const int4*>(ei + kEdges + e0 + k4);
        #define RANK1(N, O) { \
            const unsigned b_ = (unsigned)(N) >> BSHIFT; \
            const unsigned r_ = atomicAdd(&cnt[b_], 1u); \
            if (r_ < (unsigned)SLOT) { \
                slab[b_ * SLOT + r_] = \
                    (((unsigned)(N) & (BNODES - 1)) << 20) | (unsigned)(O); \
            } else { \
                const unsigned oi_ = atomicAdd(&gcur[NB * 16], 1u); \
                if (oi_ < OVFCAP) \
                    ovf[oi_] = ((unsigned long long)(unsigned)(N) << 32) | \
                               (unsigned)(O); \
            } }
        RANK1(s4.x, d4.x) RANK1(s4.y, d4.y) RANK1(s4.z, d4.z) RANK1(s4.w, d4.w)
        RANK1(d4.x, s4.x) RANK1(d4.y, s4.y) RANK1(d4.z, s4.z) RANK1(d4.w, s4.w)
        #undef RANK1
    }
    __syncthreads();

    // phase 2: per-bucket arena allocation + tail pad (tid<NB lanes only)
    if (tid < NB) {
        unsigned c = cnt[tid];
        c = c > (unsigned)SLOT ? (unsigned)SLOT : c;
        const unsigned pc = (c + 3u) & ~3u;
        pcs[tid] = pc;
        unsigned g = atomicAdd(&gcur[tid * 16], pc);
        if (g + pc > (unsigned)CAP) g = CAP - pc;   // ~20-sigma safety clamp
        dstadd[tid] = (unsigned)tid * CAP + g;
        for (unsigned j = c; j < pc; ++j) slab[tid * SLOT + j] = PADREC;
    }
    __syncthreads();

    // phase 3: NT int4 flush of live groups (arena is write-once/read-once)
    for (int k = tid; k < NB * GP; k += 1024) {
        const int b = k / GP;
        const int g4 = (k - b * GP) * 4;
        if ((unsigned)g4 < pcs[b]) {
            const u32x4 v = *reinterpret_cast<const u32x4*>(slab + b * SLOT + g4);
            __builtin_nontemporal_store(
                v, reinterpret_cast<u32x4*>(arena + dstadd[b] + g4));
        }
    }
}

__global__ __launch_bounds__(1024) void bucket_accum(
        const unsigned* __restrict__ arena, const unsigned* __restrict__ gcur,
        const unsigned* __restrict__ qtab, unsigned* __restrict__ acc) {
    __shared__ unsigned lacc[BNODES];             // 16 KB
    const int tid = threadIdx.x;
    const int b = blockIdx.x >> 1;
    const int half = blockIdx.x & 1;
    for (int k = tid; k < BNODES; k += 1024) lacc[k] = 0u;
    __syncthreads();
    unsigned len = gcur[b * 16];                  // padded records, mult of 4
    len = len > (unsigned)CAP ? (unsigned)CAP : len;
    const unsigned h = (len >> 1) & ~3u;
    const unsigned lo4 = (half ? h : 0u) >> 2;
    const unsigned hi4 = (half ? len : h) >> 2;
    const u32x4* __restrict__ p =
        reinterpret_cast<const u32x4*>(arena + (size_t)b * CAP);
    // 4-deep unrolled NT loads: 16 records + 16 gathers in flight before any
    // atomic retires -- fills the per-wave outstanding-miss queue.
    unsigned i = lo4 + tid;
    for (; i + 3072 < hi4; i += 4096) {
        const u32x4 v0 = __builtin_nontemporal_load(p + i);
        const u32x4 v1 = __builtin_nontemporal_load(p + i + 1024);
        const u32x4 v2 = __builtin_nontemporal_load(p + i + 2048);
        const u32x4 v3 = __builtin_nontemporal_load(p + i + 3072);
        unsigned q[16];
        q[0]  = qtab[v0.x & 0xFFFFFu]; q[1]  = qtab[v0.y & 0xFFFFFu];
        q[2]  = qtab[v0.z & 0xFFFFFu]; q[3]  = qtab[v0.w & 0xFFFFFu];
        q[4]  = qtab[v1.x & 0xFFFFFu]; q[5]  = qtab[v1.y & 0xFFFFFu];
        q[6]  = qtab[v1.z & 0xFFFFFu]; q[7]  = qtab[v1.w & 0xFFFFFu];
        q[8]  = qtab[v2.x & 0xFFFFFu]; q[9]  = qtab[v2.y & 0xFFFFFu];
        q[10] = qtab[v2.z & 0xFFFFFu]; q[11] = qtab[v2.w & 0xFFFFFu];
        q[12] = qtab[v3.x & 0xFFFFFu]; q[13] = qtab[v3.y & 0xFFFFFu];
        q[14] = qtab[v3.z & 0xFFFFFu]; q[15] = qtab[v3.w & 0xFFFFFu];
        atomicAdd(&lacc[v0.x >> 20], q[0]);
        atomicAdd(&lacc[v0.y >> 20], q[1]);
        atomicAdd(&lacc[v0.z >> 20], q[2]);
        atomicAdd(&lacc[v0.w >> 20], q[3]);
        atomicAdd(&lacc[v1.x >> 20], q[4]);
        atomicAdd(&lacc[v1.y >> 20], q[5]);
        atomicAdd(&lacc[v1.z >> 20], q[6]);
        atomicAdd(&lacc[v1.w >> 20], q[7]);
        atomicAdd(&lacc[v2.x >> 20], q[8]);
        atomicAdd(&lacc[v2.y >> 20], q[9]);
        atomicAdd(&lacc[v2.z >> 20], q[10]);
        atomicAdd(&lacc[v2.w >> 20], q[11]);
        atomicAdd(&lacc[v3.x >> 20], q[12]);
        atomicAdd(&lacc[v3.y >> 20], q[13]);
        atomicAdd(&lacc[v3.z >> 20], q[14]);
        atomicAdd(&lacc[v3.w >> 20], q[15]);
    }
    for (; i < hi4; i += 1024) {
        const u32x4 v = __builtin_nontemporal_load(p + i);
        atomicAdd(&lacc[v.x >> 20], qtab[v.x & 0xFFFFFu]);
        atomicAdd(&lacc[v.y >> 20], qtab[v.y & 0xFFFFFu]);
        atomicAdd(&lacc[v.z >> 20], qtab[v.z & 0xFFFFFu]);
        atomicAdd(&lacc[v.w >> 20], qtab[v.w & 0xFFFFFu]);
    }
    __syncthreads();
    const int base = b << BSHIFT;
    unsigned* __restrict__ dst = acc + (size_t)half * kNodes;
    for (int k = tid; k < BNODES; k += 1024) {
        const int nn = base + k;
        if (nn < kNodes) dst[nn] = lacc[k];
    }
}

// Exact fixup for the (statistically ~0) slab-overflow records.
__global__ __launch_bounds__(256) void ovf_fix(
        const unsigned long long* __restrict__ ovf,
        const unsigned* __restrict__ gcur, const unsigned* __restrict__ qtab,
        unsigned* __restrict__ acc) {
    unsigned n = gcur[NB * 16];
    n = n > OVFCAP ? OVFCAP : n;
    for (unsigned i = threadIdx.x; i < n; i += 256) {
        const unsigned long long v = ovf[i];
        atomicAdd(&acc[(unsigned)(v >> 32)], qtab[(unsigned)v & 0xFFFFFu]);
    }
}

// ---------------- Fallback (atomic u64) path ----------------
constexpr float kScale = 1048576.0f;           // 2^20
constexpr float kInvScale = 1.0f / 1048576.0f;
constexpr long long kBias = 1ll << 36;

__global__ __launch_bounds__(256) void zero_acc(unsigned long long* __restrict__ acc) {
    int i = blockIdx.x * 256 + threadIdx.x;
    if (i < kNodes) acc[i] = 0ull;
}

__global__ __launch_bounds__(256) void edge_kernel(
        const int* __restrict__ ei,
        const float* __restrict__ orc,
        unsigned long long* __restrict__ acc) {
    int t = blockIdx.x * 256 + threadIdx.x;
    int e0 = t * 4;
    if (e0 >= kEdges) return;
    const int4 s4 = *reinterpret_cast<const int4*>(ei + e0);
    const int4 d4 = *reinterpret_cast<const int4*>(ei + kEdges + e0);
    const int ss[4] = {s4.x, s4.y, s4.z, s4.w};
    const int dd[4] = {d4.x, d4.y, d4.z, d4.w};
    #pragma unroll
    for (int k = 0; k < 4; ++k) {
        const float os = orc[ss[k]];
        const float od = orc[dd[k]];
        const unsigned long long ps =
            (1ull << 48) + (unsigned long long)(kBias + (long long)__float2ll_rn(od * kScale));
        const unsigned long long pd =
            (1ull << 48) + (unsigned long long)(kBias + (long long)__float2ll_rn(os * kScale));
        atomicAdd(&acc[ss[k]], ps);
        atomicAdd(&acc[dd[k]], pd);
    }
}

// ---------------- Node phase ----------------
// MODE 0: u64 cell, deg<<48 | biased 2^20 fixed sum.
// MODE 3: two u32 partials, each deg<<24 | sum(q16).
template <int MODE>
__global__ __launch_bounds__(256) void node_kernel(
        const float* __restrict__ orc,
        const unsigned long long* __restrict__ acc64,
        const unsigned* __restrict__ acc32,
        const float* __restrict__ W1, const float* __restrict__ b1,
        const float* __restrict__ W2, const float* __restrict__ b2,
        const float* __restrict__ gamma, const float* __restrict__ beta,
        float* __restrict__ out) {
    const int i = blockIdx.x * 256 + threadIdx.x;
    if (i >= kNodes) return;

    const float x0 = orc[i];
    float nb;
    if (MODE == 0) {
        const unsigned long long p = acc64[i];
        const unsigned deg = (unsigned)(p >> 48);
        const long long sf = (long long)(p & ((1ull << 48) - 1)) - (long long)deg * kBias;
        const float s = (float)sf * kInvScale;
        nb = (deg > 0) ? s / (float)deg : 0.0f;
    } else {
        const unsigned p0 = acc32[i];
        const unsigned p1 = acc32[kNodes + i];
        const unsigned deg = (p0 >> 24) + (p1 >> 24);
        const unsigned sumq = (p0 & 0xFFFFFFu) + (p1 & 0xFFFFFFu);
        nb = (deg > 0)
            ? ((float)sumq * (1.0f / 32768.0f) / (float)deg - 1.0f) : 0.0f;
    }

    constexpr float kPi = 3.14159265358979323846f;
    float Phi[16];
    const float n0 = __saturatef((x0 + 1.0f) * 0.5f);
    const float n1 = __saturatef((nb + 1.0f) * 0.5f);
    #pragma unroll
    for (int k = 0; k < 4; ++k) {
        const float a0 = n0 * (float)(k + 1) * kPi;
        const float a1 = n1 * (float)(k + 1) * kPi;
        Phi[2 * k]     = __sinf(a0);
        Phi[2 * k + 1] = __cosf(a0);
        Phi[8 + 2 * k]     = __sinf(a1);
        Phi[8 + 2 * k + 1] = __cosf(a1);
    }

    float y[16];
    #pragma unroll
    for (int d = 0; d < 16; ++d) y[d] = b2[d];
    #pragma unroll
    for (int j = 0; j < 32; ++j) {
        float a = b1[j];
        #pragma unroll
        for (int d = 0; d < 16; ++d) a = fmaf(Phi[d], W1[j * 16 + d], a);
        a = fmaxf(a, 0.0f);
        #pragma unroll
        for (int d = 0; d < 16; ++d) y[d] = fmaf(a, W2[d * 32 + j], y[d]);
    }

    float mu = 0.0f;
    #pragma unroll
    for (int d = 0; d < 16; ++d) mu += y[d];
    mu *= (1.0f / 16.0f);
    float var = 0.0f;
    #pragma unroll
    for (int d = 0; d < 16; ++d) { const float t = y[d] - mu; var = fmaf(t, t, var); }
    var *= (1.0f / 16.0f);
    const float inv = rsqrtf(var + 1e-5f);

    float4* o4 = reinterpret_cast<float4*>(out + (size_t)i * 16);
    #pragma unroll
    for (int q = 0; q < 4; ++q) {
        float4 o;
        o.x = (y[4 * q + 0] - mu) * inv * gamma[4 * q + 0] + beta[4 * q + 0] + Phi[4 * q + 0];
        o.y = (y[4 * q + 1] - mu) * inv * gamma[4 * q + 1] + beta[4 * q + 1] + Phi[4 * q + 1];
        o.z = (y[4 * q + 2] - mu) * inv * gamma[4 * q + 2] + beta[4 * q + 2] + Phi[4 * q + 2];
        o.w = (y[4 * q + 3] - mu) * inv * gamma[4 * q + 3] + beta[4 * q + 3] + Phi[4 * q + 3];
        o4[q] = o;
    }
}

extern "C" void kernel_launch(void* const* d_in, const int* in_sizes, int n_in,
                              void* d_out, int out_size, void* d_ws, size_t ws_size,
                              hipStream_t stream) {
    const float* orc   = (const float*)d_in[0];
    const int*   ei    = (const int*)d_in[1];
    const float* W1    = (const float*)d_in[2];
    const float* b1    = (const float*)d_in[3];
    const float* W2    = (const float*)d_in[4];
    const float* b2    = (const float*)d_in[5];
    const float* gamma = (const float*)d_in[6];
    const float* beta  = (const float*)d_in[7];
    float* out = (float*)d_out;
    char* ws = (char*)d_ws;

    if (ws_size >= kWsNeeded) {
        unsigned* arena = (unsigned*)ws;
        unsigned* gcur = (unsigned*)(ws + kCurOff);
        unsigned* acc = (unsigned*)(ws + kAccOff);
        unsigned* qtab = (unsigned*)(ws + kQtabOff);
        unsigned long long* ovf = (unsigned long long*)(ws + kOvfOff);
        qtab_build<<<QTABN / 4 / 256, 256, 0, stream>>>(orc, qtab, gcur);
        scatter_sort<<<TILES, 1024, 0, stream>>>(ei, arena, gcur, ovf);
        bucket_accum<<<NBUSED * SPLIT, 1024, 0, stream>>>(arena, gcur, qtab, acc);
        ovf_fix<<<1, 256, 0, stream>>>(ovf, gcur, qtab, acc);
        node_kernel<3><<<(kNodes + 255) / 256, 256, 0, stream>>>(
            orc, nullptr, acc, W1, b1, W2, b2, gamma, beta, out);
    } else {
        unsigned long long* acc = (unsigned long long*)ws;  // 8 MB
        zero_acc<<<(kNodes + 255) / 256, 256, 0, stream>>>(acc);
        edge_kernel<<<(kEdges / 4 + 255) / 256, 256, 0, stream>>>(ei, orc, acc);
        node_kernel<0><<<(kNodes + 255) / 256, 256, 0, stream>>>(
            orc, acc, nullptr, W1, b1, W2, b2, gamma, beta, out);
    }
}

// Round 11
// 696.722 us; speedup vs baseline: 1.3482x; 1.3482x over previous
//
#include <hip/hip_runtime.h>

constexpr int kNodes = 1000000;
constexpr int kEdges = 32000000;

// ---------------- Tile-sorted scatter path (R5 structure + tuned accum) ----
// 256 buckets x 4096 nodes. Record u32 = (node&4095)<<16 | q16,
// q16 = clamp(round((orc_other+1)*32768), 0, 65535)  (error <= 1.5e-5).
// Producer (per 4096-edge tile): fixed 72-slot LDS slab per bucket; rank
// atomic r=atomicAdd(cnt[b]) places the record at slab[b*72+r] directly
// (one LDS atomic per record, no histogram pass). Overflow (~1e-8/segment)
// -> global list + exact fixup. Arena allocation: one atomicAdd(gcur[b],
// paddedcount) per bucket -> 16B-aligned contiguous run; plain int4 flush
// (keeps arena L2/L3-resident for the consumer -- NT stores hurt, R10).
// Consumer: SPLIT=4 quarters per bucket (980 blocks = 3.83/CU; fixes the
// 1.91/CU packing imbalance measured in R9/R10), NONTEMPORAL 4-deep
// unrolled uint4 loads (R10: -10% time, -45% FETCH), dual LDS accumulator
// copies; pads hit a sink slot branchlessly.
// Calibrations: R6 direct global atomics = 2.4 ms for 64M (memory-side).
// R9/R10: id-record + consumer-side gathers = net loss; value-records win.
constexpr int NB = 256;
constexpr int BSHIFT = 12;
constexpr int BNODES = 4096;
constexpr int NBUSED = (kNodes + BNODES - 1) / BNODES;   // 245
constexpr int EPT = 4096;                 // edges per tile
constexpr int TILES = (kEdges + EPT - 1) / EPT;          // 7813
constexpr int SLOT = 72;                  // slab slots/bucket (72%32=8: low conflict)
constexpr int GP = SLOT / 4;              // int4 groups per slab (18)
constexpr int CAP = 276480;               // per-bucket arena capacity (mult 4)
                                          // mean padded ~269.5K -> ~14 sigma
constexpr int SPLIT = 4;                  // quarters per bucket in accum
constexpr unsigned PADREC = 0x10000000u;  // local node 4096 -> LDS sink slot
constexpr unsigned OVFCAP = 8192;

typedef unsigned u32x4 __attribute__((ext_vector_type(4)));  // NT-capable vec

constexpr size_t kArenaBytes = (size_t)NBUSED * CAP * 4;   // ~271 MB
constexpr size_t kCurOff    = kArenaBytes;
constexpr size_t kCurBytes  = (size_t)NB * 64 + 64;        // strided cursors + ovfcnt
constexpr size_t kAccOff    = kCurOff + kCurBytes;
constexpr size_t kAccBytes  = (size_t)SPLIT * kNodes * 4;  // 16 MB
constexpr size_t kOrcqOff   = kAccOff + kAccBytes;
constexpr size_t kOrcqBytes = (size_t)kNodes * 2;          // 2 MB
constexpr size_t kOvfOff    = (kOrcqOff + kOrcqBytes + 7) & ~(size_t)7;
constexpr size_t kOvfBytes  = (size_t)OVFCAP * 8;          // 64 KB
constexpr size_t kWsNeeded  = kOvfOff + kOvfBytes;         // ~289 MB

__global__ __launch_bounds__(256) void quant_orc(
        const float* __restrict__ orc, unsigned short* __restrict__ orcq,
        unsigned* __restrict__ gcur) {
    if (blockIdx.x == 0) {
        if (threadIdx.x < NB) gcur[threadIdx.x * 16] = 0u;
        if (threadIdx.x == 0) gcur[NB * 16] = 0u;       // overflow counter
    }
    const int i = (blockIdx.x * 256 + threadIdx.x) * 4;
    if (i >= kNodes) return;
    const float4 v = *reinterpret_cast<const float4*>(orc + i);
    unsigned q0 = __float2uint_rn((v.x + 1.0f) * 32768.0f);
    unsigned q1 = __float2uint_rn((v.y + 1.0f) * 32768.0f);
    unsigned q2 = __float2uint_rn((v.z + 1.0f) * 32768.0f);
    unsigned q3 = __float2uint_rn((v.w + 1.0f) * 32768.0f);
    q0 = q0 > 65535u ? 65535u : q0;
    q1 = q1 > 65535u ? 65535u : q1;
    q2 = q2 > 65535u ? 65535u : q2;
    q3 = q3 > 65535u ? 65535u : q3;
    ushort4 q;
    q.x = (unsigned short)q0; q.y = (unsigned short)q1;
    q.z = (unsigned short)q2; q.w = (unsigned short)q3;
    *reinterpret_cast<ushort4*>(orcq + i) = q;
}

__global__ __launch_bounds__(1024) void scatter_sort(
        const int* __restrict__ ei, const unsigned short* __restrict__ orcq,
        unsigned* __restrict__ arena, unsigned* __restrict__ gcur,
        unsigned long long* __restrict__ ovf) {
    __shared__ alignas(16) unsigned slab[NB * SLOT];   // 72 KB fixed slabs
    __shared__ unsigned cnt[NB];                       // rank cursors
    __shared__ unsigned pcs[NB];                       // padded counts
    __shared__ unsigned dstadd[NB];                    // arena dst base
    const int tid = threadIdx.x;
    const int t = blockIdx.x;
    const int e0 = t * EPT;
    const int ne = min(EPT, kEdges - e0);   // 4096; last tile 2048
    const int k4 = tid * 4;

    if (tid < NB) cnt[tid] = 0u;
    __syncthreads();

    // phase 1: edges -> registers, orcq gathers, rank + slab store.
    // ONE LDS atomic per record (no histogram pass).
    if (k4 < ne) {
        const int4 s4 = *reinterpret_cast<const int4*>(ei + e0 + k4);
        const int4 d4 = *reinterpret_cast<const int4*>(ei + kEdges + e0 + k4);
        const unsigned a0 = orcq[d4.x], a1 = orcq[d4.y],
                       a2 = orcq[d4.z], a3 = orcq[d4.w];   // q(orc[d]) -> s-rec
        const unsigned b0 = orcq[s4.x], b1 = orcq[s4.y],
                       b2 = orcq[s4.z], b3 = orcq[s4.w];   // q(orc[s]) -> d-rec
        #define RANK1(N, Q) { \
            const unsigned b_ = (unsigned)(N) >> BSHIFT; \
            const unsigned r_ = atomicAdd(&cnt[b_], 1u); \
            if (r_ < (unsigned)SLOT) { \
                slab[b_ * SLOT + r_] = (((unsigned)(N) & (BNODES - 1)) << 16) | (Q); \
            } else { \
                const unsigned oi_ = atomicAdd(&gcur[NB * 16], 1u); \
                if (oi_ < OVFCAP) \
                    ovf[oi_] = ((unsigned long long)(unsigned)(N) << 16) | (Q); \
            } }
        RANK1(s4.x, a0) RANK1(s4.y, a1) RANK1(s4.z, a2) RANK1(s4.w, a3)
        RANK1(d4.x, b0) RANK1(d4.y, b1) RANK1(d4.z, b2) RANK1(d4.w, b3)
        #undef RANK1
    }
    __syncthreads();

    // phase 2: per-bucket arena allocation (independent atomics, no scan),
    // pad fill to multiple of 4 records so every int4 group is one bucket.
    if (tid < NB) {
        unsigned c = cnt[tid];
        c = c > (unsigned)SLOT ? (unsigned)SLOT : c;
        const unsigned pc = (c + 3u) & ~3u;
        pcs[tid] = pc;
        unsigned g = atomicAdd(&gcur[tid * 16], pc);
        if (g + pc > (unsigned)CAP) g = CAP - pc;   // ~14-sigma safety clamp
        dstadd[tid] = (unsigned)tid * CAP + g;
        for (unsigned j = c; j < pc; ++j) slab[tid * SLOT + j] = PADREC;
    }
    __syncthreads();

    // phase 3: plain int4 flush (arena stays L2/L3-resident for the consumer)
    for (int k = tid; k < NB * GP; k += 1024) {
        const int b = k / GP;
        const int g4 = (k - b * GP) * 4;
        if ((unsigned)g4 < pcs[b]) {
            *reinterpret_cast<int4*>(arena + dstadd[b] + g4) =
                *reinterpret_cast<const int4*>(slab + b * SLOT + g4);
        }
    }
}

__global__ __launch_bounds__(1024) void bucket_accum(
        const unsigned* __restrict__ arena, const unsigned* __restrict__ gcur,
        unsigned* __restrict__ acc) {
    __shared__ unsigned lacc[2][BNODES + 4];     // dual copies; slot 4096 = sink
    unsigned* __restrict__ flat = &lacc[0][0];
    const int tid = threadIdx.x;
    const int b = blockIdx.x >> 2;               // SPLIT = 4
    const int quar = blockIdx.x & 3;
    for (int k = tid; k < 2 * (BNODES + 4); k += 1024) flat[k] = 0u;
    __syncthreads();
    unsigned* __restrict__ my = lacc[(tid >> 6) & 1];
    unsigned len = gcur[b * 16];                 // padded records, mult of 4
    len = len > (unsigned)CAP ? (unsigned)CAP : len;
    const unsigned n4 = len >> 2;
    const unsigned lo4 = ((unsigned)quar * n4) >> 2;
    const unsigned hi4 = ((unsigned)(quar + 1) * n4) >> 2;
    const u32x4* __restrict__ p =
        reinterpret_cast<const u32x4*>(arena + (size_t)b * CAP);
    // 4-deep unrolled NT loads: 16 records in flight per thread; NT keeps
    // the single-use stream from evicting hot lines (R10: -10%, -45% FETCH).
    unsigned i = lo4 + tid;
    for (; i + 3072 < hi4; i += 4096) {
        const u32x4 v0 = __builtin_nontemporal_load(p + i);
        const u32x4 v1 = __builtin_nontemporal_load(p + i + 1024);
        const u32x4 v2 = __builtin_nontemporal_load(p + i + 2048);
        const u32x4 v3 = __builtin_nontemporal_load(p + i + 3072);
        atomicAdd(&my[v0.x >> 16], (v0.x & 0xFFFFu) | 0x1000000u);
        atomicAdd(&my[v0.y >> 16], (v0.y & 0xFFFFu) | 0x1000000u);
        atomicAdd(&my[v0.z >> 16], (v0.z & 0xFFFFu) | 0x1000000u);
        atomicAdd(&my[v0.w >> 16], (v0.w & 0xFFFFu) | 0x1000000u);
        atomicAdd(&my[v1.x >> 16], (v1.x & 0xFFFFu) | 0x1000000u);
        atomicAdd(&my[v1.y >> 16], (v1.y & 0xFFFFu) | 0x1000000u);
        atomicAdd(&my[v1.z >> 16], (v1.z & 0xFFFFu) | 0x1000000u);
        atomicAdd(&my[v1.w >> 16], (v1.w & 0xFFFFu) | 0x1000000u);
        atomicAdd(&my[v2.x >> 16], (v2.x & 0xFFFFu) | 0x1000000u);
        atomicAdd(&my[v2.y >> 16], (v2.y & 0xFFFFu) | 0x1000000u);
        atomicAdd(&my[v2.z >> 16], (v2.z & 0xFFFFu) | 0x1000000u);
        atomicAdd(&my[v2.w >> 16], (v2.w & 0xFFFFu) | 0x1000000u);
        atomicAdd(&my[v3.x >> 16], (v3.x & 0xFFFFu) | 0x1000000u);
        atomicAdd(&my[v3.y >> 16], (v3.y & 0xFFFFu) | 0x1000000u);
        atomicAdd(&my[v3.z >> 16], (v3.z & 0xFFFFu) | 0x1000000u);
        atomicAdd(&my[v3.w >> 16], (v3.w & 0xFFFFu) | 0x1000000u);
    }
    for (; i < hi4; i += 1024) {
        const u32x4 v = __builtin_nontemporal_load(p + i);
        atomicAdd(&my[v.x >> 16], (v.x & 0xFFFFu) | 0x1000000u);
        atomicAdd(&my[v.y >> 16], (v.y & 0xFFFFu) | 0x1000000u);
        atomicAdd(&my[v.z >> 16], (v.z & 0xFFFFu) | 0x1000000u);
        atomicAdd(&my[v.w >> 16], (v.w & 0xFFFFu) | 0x1000000u);
    }
    __syncthreads();
    const int base = b << BSHIFT;
    unsigned* __restrict__ dst = acc + (size_t)quar * kNodes;
    for (int k = tid; k < BNODES; k += 1024) {
        const int nn = base + k;
        if (nn < kNodes) dst[nn] = lacc[0][k] + lacc[1][k];
    }
}

// Exact fixup for the (statistically ~0.1 expected) slab-overflow records.
__global__ __launch_bounds__(256) void ovf_fix(
        const unsigned long long* __restrict__ ovf,
        const unsigned* __restrict__ gcur, unsigned* __restrict__ acc) {
    unsigned n = gcur[NB * 16];
    n = n > OVFCAP ? OVFCAP : n;
    for (unsigned i = threadIdx.x; i < n; i += 256) {
        const unsigned long long v = ovf[i];
        atomicAdd(&acc[(unsigned)(v >> 16)],
                  ((unsigned)v & 0xFFFFu) | 0x1000000u);
    }
}

// ---------------- Fallback (atomic u64) path ----------------
constexpr float kScale = 1048576.0f;           // 2^20
constexpr float kInvScale = 1.0f / 1048576.0f;
constexpr long long kBias = 1ll << 36;

__global__ __launch_bounds__(256) void zero_acc(unsigned long long* __restrict__ acc) {
    int i = blockIdx.x * 256 + threadIdx.x;
    if (i < kNodes) acc[i] = 0ull;
}

__global__ __launch_bounds__(256) void edge_kernel(
        const int* __restrict__ ei,
        const float* __restrict__ orc,
        unsigned long long* __restrict__ acc) {
    int t = blockIdx.x * 256 + threadIdx.x;
    int e0 = t * 4;
    if (e0 >= kEdges) return;
    const int4 s4 = *reinterpret_cast<const int4*>(ei + e0);
    const int4 d4 = *reinterpret_cast<const int4*>(ei + kEdges + e0);
    const int ss[4] = {s4.x, s4.y, s4.z, s4.w};
    const int dd[4] = {d4.x, d4.y, d4.z, d4.w};
    #pragma unroll
    for (int k = 0; k < 4; ++k) {
        const float os = orc[ss[k]];
        const float od = orc[dd[k]];
        const unsigned long long ps =
            (1ull << 48) + (unsigned long long)(kBias + (long long)__float2ll_rn(od * kScale));
        const unsigned long long pd =
            (1ull << 48) + (unsigned long long)(kBias + (long long)__float2ll_rn(os * kScale));
        atomicAdd(&acc[ss[k]], ps);
        atomicAdd(&acc[dd[k]], pd);
    }
}

// ---------------- Node phase ----------------
// MODE 0: u64 cell, deg<<48 | biased 2^20 fixed sum.
// MODE 5: SPLIT u32 partials, each deg<<24 | sum(q16).
template <int MODE>
__global__ __launch_bounds__(256) void node_kernel(
        const float* __restrict__ orc,
        const unsigned long long* __restrict__ acc64,
        const unsigned* __restrict__ acc32,
        const float* __restrict__ W1, const float* __restrict__ b1,
        const float* __restrict__ W2, const float* __restrict__ b2,
        const float* __restrict__ gamma, const float* __restrict__ beta,
        float* __restrict__ out) {
    const int i = blockIdx.x * 256 + threadIdx.x;
    if (i >= kNodes) return;

    const float x0 = orc[i];
    float nb;
    if (MODE == 0) {
        const unsigned long long p = acc64[i];
        const unsigned deg = (unsigned)(p >> 48);
        const long long sf = (long long)(p & ((1ull << 48) - 1)) - (long long)deg * kBias;
        const float s = (float)sf * kInvScale;
        nb = (deg > 0) ? s / (float)deg : 0.0f;
    } else {
        unsigned deg = 0u, sumq = 0u;
        #pragma unroll
        for (int r = 0; r < SPLIT; ++r) {
            const unsigned p = acc32[(size_t)r * kNodes + i];
            deg += p >> 24;
            sumq += p & 0xFFFFFFu;
        }
        nb = (deg > 0)
            ? ((float)sumq * (1.0f / 32768.0f) / (float)deg - 1.0f) : 0.0f;
    }

    constexpr float kPi = 3.14159265358979323846f;
    float Phi[16];
    const float n0 = __saturatef((x0 + 1.0f) * 0.5f);
    const float n1 = __saturatef((nb + 1.0f) * 0.5f);
    #pragma unroll
    for (int k = 0; k < 4; ++k) {
        const float a0 = n0 * (float)(k + 1) * kPi;
        const float a1 = n1 * (float)(k + 1) * kPi;
        Phi[2 * k]     = __sinf(a0);
        Phi[2 * k + 1] = __cosf(a0);
        Phi[8 + 2 * k]     = __sinf(a1);
        Phi[8 + 2 * k + 1] = __cosf(a1);
    }

    float y[16];
    #pragma unroll
    for (int d = 0; d < 16; ++d) y[d] = b2[d];
    #pragma unroll
    for (int j = 0; j < 32; ++j) {
        float a = b1[j];
        #pragma unroll
        for (int d = 0; d < 16; ++d) a = fmaf(Phi[d], W1[j * 16 + d], a);
        a = fmaxf(a, 0.0f);
        #pragma unroll
        for (int d = 0; d < 16; ++d) y[d] = fmaf(a, W2[d * 32 + j], y[d]);
    }

    float mu = 0.0f;
    #pragma unroll
    for (int d = 0; d < 16; ++d) mu += y[d];
    mu *= (1.0f / 16.0f);
    float var = 0.0f;
    #pragma unroll
    for (int d = 0; d < 16; ++d) { const float t = y[d] - mu; var = fmaf(t, t, var); }
    var *= (1.0f / 16.0f);
    const float inv = rsqrtf(var + 1e-5f);

    float4* o4 = reinterpret_cast<float4*>(out + (size_t)i * 16);
    #pragma unroll
    for (int q = 0; q < 4; ++q) {
        float4 o;
        o.x = (y[4 * q + 0] - mu) * inv * gamma[4 * q + 0] + beta[4 * q + 0] + Phi[4 * q + 0];
        o.y = (y[4 * q + 1] - mu) * inv * gamma[4 * q + 1] + beta[4 * q + 1] + Phi[4 * q + 1];
        o.z = (y[4 * q + 2] - mu) * inv * gamma[4 * q + 2] + beta[4 * q + 2] + Phi[4 * q + 2];
        o.w = (y[4 * q + 3] - mu) * inv * gamma[4 * q + 3] + beta[4 * q + 3] + Phi[4 * q + 3];
        o4[q] = o;
    }
}

extern "C" void kernel_launch(void* const* d_in, const int* in_sizes, int n_in,
                              void* d_out, int out_size, void* d_ws, size_t ws_size,
                              hipStream_t stream) {
    const float* orc   = (const float*)d_in[0];
    const int*   ei    = (const int*)d_in[1];
    const float* W1    = (const float*)d_in[2];
    const float* b1    = (const float*)d_in[3];
    const float* W2    = (const float*)d_in[4];
    const float* b2    = (const float*)d_in[5];
    const float* gamma = (const float*)d_in[6];
    const float* beta  = (const float*)d_in[7];
    float* out = (float*)d_out;
    char* ws = (char*)d_ws;

    if (ws_size >= kWsNeeded) {
        unsigned* arena = (unsigned*)ws;
        unsigned* gcur = (unsigned*)(ws + kCurOff);
        unsigned* acc = (unsigned*)(ws + kAccOff);
        unsigned short* orcq = (unsigned short*)(ws + kOrcqOff);
        unsigned long long* ovf = (unsigned long long*)(ws + kOvfOff);
        quant_orc<<<(kNodes / 4 + 255) / 256, 256, 0, stream>>>(orc, orcq, gcur);
        scatter_sort<<<TILES, 1024, 0, stream>>>(ei, orcq, arena, gcur, ovf);
        bucket_accum<<<NBUSED * SPLIT, 1024, 0, stream>>>(arena, gcur, acc);
        ovf_fix<<<1, 256, 0, stream>>>(ovf, gcur, acc);
        node_kernel<5><<<(kNodes + 255) / 256, 256, 0, stream>>>(
            orc, nullptr, acc, W1, b1, W2, b2, gamma, beta, out);
    } else {
        unsigned long long* acc = (unsigned long long*)ws;  // 8 MB
        zero_acc<<<(kNodes + 255) / 256, 256, 0, stream>>>(acc);
        edge_kernel<<<(kEdges / 4 + 255) / 256, 256, 0, stream>>>(ei, orc, acc);
        node_kernel<0><<<(kNodes + 255) / 256, 256, 0, stream>>>(
            orc, acc, nullptr, W1, b1, W2, b2, gamma, beta, out);
    }
}